// Round 8
// baseline (254.133 us; speedup 1.0000x reference)
//
#include <hip/hip_runtime.h>

#define KK 32
#define KP 33
#define NMAXC 256
#define BCH 32            // bsz * ENS
#define NPADC 32768
#define TARGETC 32640
#define LSEG 64           // items per segment
#define MSEG 512          // NPADC / LSEG
#define GSZ 32            // segments per group
#define NG 16             // MSEG / GSZ
#define SS 2

#define OFFS(i) ((i)*255 - (i)*((i)-1)/2)

// ---- cross-lane helpers on the VALU pipe (no ds_bpermute) ----
__device__ __forceinline__ int dpp_shr1_i(int v) {
    // wave_shr:1 (0x138), bound_ctrl=1 -> lane 0 receives 0
    return __builtin_amdgcn_mov_dpp(v, 0x138, 0xf, 0xf, true);
}
__device__ __forceinline__ double dpp_shr1_d(double v) {
    union { double d; int i[2]; } u; u.d = v;
    u.i[0] = dpp_shr1_i(u.i[0]);
    u.i[1] = dpp_shr1_i(u.i[1]);
    return u.d;
}
__device__ __forceinline__ double readlane_d(double v, int l) {
    union { double d; int i[2]; } u; u.d = v;
    union { double d; int i[2]; } r;
    r.i[0] = __builtin_amdgcn_readlane(u.i[0], l);
    r.i[1] = __builtin_amdgcn_readlane(u.i[1], l);
    return r.d;
}
__device__ __forceinline__ double readlane_f_to_d(float v, int l) {
    union { float f; int i; } u; u.f = v;
    union { float f; int i; } r;
    r.i = __builtin_amdgcn_readlane(u.i, l);
    return (double)r.f;
}

__device__ __forceinline__ void decode_ij(int t, int& oi, int& oj) {
    int ii = (int)((511.0 - sqrt(511.0 * 511.0 - 8.0 * (double)t)) * 0.5);
    if (ii < 0) ii = 0;
    if (ii > 254) ii = 254;
    while (ii < 254 && OFFS(ii + 1) <= t) ++ii;
    while (ii > 0 && OFFS(ii) > t) --ii;
    oi = ii;
    oj = t - OFFS(ii) + ii + 1;
}

// 33-point truncated polynomial product: out[r] = sum_j a[j]*b[r-j].
// a read via readlane (dependent operand), b rotated via DPP (independent).
__device__ __forceinline__ double conv33_rb(double a_dep, double b_rot) {
    double s0 = 0.0, s1 = 0.0, s2 = 0.0, s3 = 0.0;
    double brot = b_rot;
#pragma unroll
    for (int j = 0; j < KP; ++j) {
        double aj = readlane_d(a_dep, j);
        switch (j & 3) {
            case 0: s0 = fma(aj, brot, s0); break;
            case 1: s1 = fma(aj, brot, s1); break;
            case 2: s2 = fma(aj, brot, s2); break;
            default: s3 = fma(aj, brot, s3); break;
        }
        brot = dpp_shr1_d(brot);
    }
    return (s0 + s1) + (s2 + s3);
}

// ---- kernel 1: fused exp(theta) + per-segment elementary symmetric polys
__global__ void k_prep(const float* __restrict__ sc, double* __restrict__ X,
                       double* __restrict__ Bp) {
    int lane = threadIdx.x & 63;
    int blk = blockIdx.x * 4 + (threadIdx.x >> 6);   // b*MSEG + m
    int b = blk >> 9, m = blk & (MSEG - 1);
    int t = m * LSEG + lane;
    double x = 0.0;
    if (t < TARGETC) {
        int i, j;
        decode_ij(t, i, j);
        double th = (double)sc[((size_t)b * NMAXC + i) * NMAXC + j] +
                    (double)sc[((size_t)b * NMAXC + j) * NMAXC + i];
        x = exp(th);
    }
    X[(size_t)b * NPADC + t] = x;
    double c = (lane == 0) ? 1.0 : 0.0;
#pragma unroll
    for (int j = 0; j < LSEG; ++j) {
        double xj = readlane_d(x, j);
        double up = dpp_shr1_d(c);                   // lane0 -> 0
        c = fma(xj, up, c);
    }
    if (lane < KP) Bp[(size_t)blk * KP + lane] = c;
}

// ---- kernel 2: suffix-inclusive scan within group (1 wave/block, 512 blocks)
__global__ void k_gpart(const double* __restrict__ Bp,
                        double* __restrict__ sfxI, double* __restrict__ gpoly) {
    int lane = threadIdx.x;
    int blk = blockIdx.x;                 // b*NG + g
    int b = blk / NG, g = blk % NG;
    double run = (lane == 0) ? 1.0 : 0.0;
    int m = g * GSZ + (GSZ - 1);
    double bp = (lane < KP) ? Bp[((size_t)b * MSEG + m) * KP + lane] : 0.0;
    for (int i = GSZ - 1; i >= 0; --i) {
        int mi = g * GSZ + i;
        double bpn = (i > 0 && lane < KP) ? Bp[((size_t)b * MSEG + mi - 1) * KP + lane] : 0.0;
        run = conv33_rb(run, bp);         // dependent operand via readlane
        if (lane < KP) sfxI[((size_t)b * MSEG + mi) * KP + lane] = run;
        bp = bpn;
    }
    if (lane < KP) gpoly[(size_t)blk * KP + lane] = run;
}

// ---- kernel 3: suffix scan over group polys (exclusive carries) + full Z poly
__global__ void k_gscan(const double* __restrict__ gpoly, double* __restrict__ gcarry,
                        double* __restrict__ eZ) {
    int lane = threadIdx.x;
    int b = blockIdx.x;
    double run = (lane == 0) ? 1.0 : 0.0;
    double gp = (lane < KP) ? gpoly[((size_t)b * NG + NG - 1) * KP + lane] : 0.0;
    for (int g = NG - 1; g >= 0; --g) {
        if (lane < KP) gcarry[((size_t)b * NG + g) * KP + lane] = run;
        double gpn = (g > 0 && lane < KP) ? gpoly[((size_t)b * NG + g - 1) * KP + lane] : 0.0;
        run = conv33_rb(run, gp);
        gp = gpn;
    }
    if (lane < KP) eZ[(size_t)b * KP + lane] = run;   // e_0..e_K of all items
}

// ---- kernel 4: backward sfx sweep fused with sampling; entry checkpoint
//      reconstructed in-kernel (chkpt fused). 4 segments / block.
__global__ void k_backward(const double* __restrict__ X, const double* __restrict__ sfxI,
                           const double* __restrict__ gcarry, const float* __restrict__ U,
                           unsigned long long* __restrict__ masks, int* __restrict__ tab) {
    int lane = threadIdx.x & 63;
    int blk = blockIdx.x * 4 + (threadIdx.x >> 6);   // b*MSEG + m
    int b = blk >> 9, m = blk & (MSEG - 1);
    double xa = X[(size_t)b * NPADC + (size_t)m * LSEG + lane];
    float uf0 = U[((size_t)0 * NPADC + (size_t)m * LSEG + lane) * BCH + b];
    float uf1 = U[((size_t)1 * NPADC + (size_t)m * LSEG + lane) * BCH + b];
    double c;
    if (m + 1 == MSEG) {
        c = (lane == 0) ? 1.0 : 0.0;
    } else {
        double a  = (lane < KP) ? sfxI[((size_t)b * MSEG + m + 1) * KP + lane] : 0.0;
        double cg = (lane < KP) ? gcarry[((size_t)b * NG + (m + 1) / GSZ) * KP + lane] : 0.0;
        c = conv33_rb(cg, a);             // same op order as round-7 k_chkpt
        c = (lane < KP) ? c : 0.0;        // keep lanes>=33 identical to prior rounds
    }
    int S0 = lane, S1 = lane;
    unsigned long long mk0 = 0, mk1 = 0;
#pragma unroll
    for (int j = LSEG - 1; j >= 0; --j) {
        double xj = readlane_d(xa, j);
        double up = dpp_shr1_d(c);                   // sfx[j+1][lane-1], lane0 -> 0
        double rhs = xj * up;
        double cn = fma(xj, up, c);                  // sfx[j][lane]
        double ud0 = readlane_f_to_d(uf0, j);
        double ud1 = readlane_f_to_d(uf1, j);
        bool i0 = (ud0 * cn < rhs);                  // lane0: rhs==0 -> false
        bool i1 = (ud1 * cn < rhs);
        unsigned long long b0 = __ballot(i0);
        unsigned long long b1 = __ballot(i1);
        if (lane == j) { mk0 = b0; mk1 = b1; }       // SGPR->VGPR cndmask, no LDS
        int t0 = dpp_shr1_i(S0);
        int t1 = dpp_shr1_i(S1);
        if (i0) S0 = t0;
        if (i1) S1 = t1;
        c = cn;
    }
    size_t sb0 = (size_t)blk;
    size_t sb1 = (size_t)BCH * MSEG + blk;
    masks[sb0 * LSEG + lane] = mk0;
    masks[sb1 * LSEG + lane] = mk1;
    if (lane < KP) {
        tab[sb0 * KP + lane] = S0;
        tab[sb1 * KP + lane] = S1;
    }
}

// ---- kernel 5: fused hierarchical compose + mask replay -> packed bitset
__global__ void __launch_bounds__(1024) k_creplay(const int* __restrict__ tab,
                                                  const unsigned long long* __restrict__ masks,
                                                  unsigned long long* __restrict__ bitflat) {
    __shared__ int gtab[NG][KP];
    __shared__ int gent[NG];
    int sb = blockIdx.x;                  // s*BCH + b
    int tid = threadIdx.x;                // 1024
    int w = tid >> 6, lane = tid & 63;
    int tv[GSZ];
    const int* base = tab + ((size_t)sb * MSEG + w * GSZ) * KP;
#pragma unroll
    for (int i = 0; i < GSZ; ++i)
        tv[i] = (lane < KP) ? base[i * KP + lane] : 0;
    int T = lane;                         // compose this wave's 32 segment maps
#pragma unroll
    for (int i = 0; i < GSZ; ++i)
        T = __shfl(tv[i], T, 64);
    if (lane < KP) gtab[w][lane] = T;
    __syncthreads();
    if (tid == 0) {
        int r = KK;
        for (int g = 0; g < NG; ++g) { gent[g] = r; r = gtab[g][r]; }
    }
    __syncthreads();
    int r = __builtin_amdgcn_readfirstlane(gent[w]);
    // walk the wave's 32 segments: replay masks bit-by-bit (scalar), prefetch 1-deep
    size_t segBase = (size_t)sb * MSEG + w * GSZ;
    unsigned long long mv = masks[segBase * LSEG + lane];
    for (int i = 0; i < GSZ; ++i) {
        unsigned long long mvn = (i + 1 < GSZ) ? masks[(segBase + i + 1) * LSEG + lane] : 0;
        int mlo = (int)(unsigned)mv;
        int mhi = (int)(unsigned)(mv >> 32);
        unsigned long long sel = 0;
#pragma unroll
        for (int j = 0; j < LSEG; ++j) {
            unsigned lo = (unsigned)__builtin_amdgcn_readlane(mlo, j);
            unsigned hi = (unsigned)__builtin_amdgcn_readlane(mhi, j);
            unsigned long long mj = ((unsigned long long)hi << 32) | lo;
            int inc = (int)((mj >> r) & 1ull);
            sel |= ((unsigned long long)inc) << j;
            r -= inc;
        }
        if (lane == 0) bitflat[segBase + i] = sel;
        mv = mvn;
    }
}

// ---- kernel 6: combined output emission.
//      gridDim.y in [0, SS*BCH): mask rows for chain sb = y
//      gridDim.y in [SS*BCH, SS*BCH+BCH): marginal rows for batch b = y - SS*BCH
__global__ void k_emit(const unsigned long long* __restrict__ bitflat,
                       const double* __restrict__ X, const double* __restrict__ eZ,
                       float* __restrict__ outMask, float* __restrict__ outMarg) {
    __shared__ unsigned long long bf[MSEG];
    __shared__ double e[KP];
    __shared__ double invZ;
    int y = blockIdx.y;
    int i = blockIdx.x;
    int j = threadIdx.x;                  // 256
    if (y < SS * BCH) {
        int sb = y;
        bf[j] = bitflat[(size_t)sb * MSEG + j];
        bf[j + 256] = bitflat[(size_t)sb * MSEG + 256 + j];
        __syncthreads();
        float v = 0.0f;
        if (j > i) {
            int t = OFFS(i) + j - i - 1;
            v = (float)((bf[t >> 6] >> (t & 63)) & 1ull);
        } else if (j < i) {
            int t = OFFS(j) + i - j - 1;
            v = (float)((bf[t >> 6] >> (t & 63)) & 1ull);
        }
        outMask[((size_t)sb * NMAXC + i) * NMAXC + j] = v;
    } else {
        int b = y - SS * BCH;
        if (j < KP) e[j] = eZ[(size_t)b * KP + j];
        __syncthreads();
        if (j == 0) invZ = 1.0 / e[KK];
        __syncthreads();
        float v = 0.0f;
        if (i != j) {
            int t = (j > i) ? (OFFS(i) + j - i - 1) : (OFFS(j) + i - j - 1);
            double x = X[(size_t)b * NPADC + t];
            double f = 1.0;
#pragma unroll
            for (int k = 1; k < KK; ++k) f = fma(-x, f, e[k]);
            v = (float)(x * f * invZ);
        }
        outMarg[((size_t)b * NMAXC + i) * NMAXC + j] = v;
    }
}

extern "C" void kernel_launch(void* const* d_in, const int* in_sizes, int n_in,
                              void* d_out, int out_size, void* d_ws, size_t ws_size,
                              hipStream_t stream) {
    const float* scores = (const float*)d_in[0];
    const float* uniforms = (const float*)d_in[1];

    char* ws = (char*)d_ws;
    size_t off = 0;
    auto alloc = [&](size_t bytes) {
        void* p = ws + off;
        off += (bytes + 255) & ~(size_t)255;
        return p;
    };
    double* X      = (double*)alloc((size_t)BCH * NPADC * 8);
    double* Bp     = (double*)alloc((size_t)BCH * MSEG * KP * 8);
    double* sfxI   = (double*)alloc((size_t)BCH * MSEG * KP * 8);
    double* gpoly  = (double*)alloc((size_t)BCH * NG * KP * 8);
    double* gcarry = (double*)alloc((size_t)BCH * NG * KP * 8);
    double* eZ     = (double*)alloc((size_t)BCH * KP * 8);
    unsigned long long* masks = (unsigned long long*)alloc((size_t)SS * BCH * MSEG * LSEG * 8);
    int* tab       = (int*)alloc((size_t)SS * BCH * MSEG * KP * 4);
    unsigned long long* bitflat = (unsigned long long*)alloc((size_t)SS * BCH * MSEG * 8);
    if (off > ws_size) return;            // ~38 MB

    k_prep<<<BCH * MSEG / 4, 256, 0, stream>>>(scores, X, Bp);
    k_gpart<<<BCH * NG, 64, 0, stream>>>(Bp, sfxI, gpoly);
    k_gscan<<<BCH, 64, 0, stream>>>(gpoly, gcarry, eZ);
    k_backward<<<BCH * MSEG / 4, 256, 0, stream>>>(X, sfxI, gcarry, uniforms, masks, tab);
    k_creplay<<<SS * BCH, 1024, 0, stream>>>(tab, masks, bitflat);
    k_emit<<<dim3(NMAXC, SS * BCH + BCH), 256, 0, stream>>>(
        bitflat, X, eZ, (float*)d_out,
        (float*)d_out + (size_t)SS * BCH * NMAXC * NMAXC);
}

// Round 9
// 160.393 us; speedup vs baseline: 1.5844x; 1.5844x over previous
//
#include <hip/hip_runtime.h>

#define KK 32
#define KP 33
#define NMAXC 256
#define BCH 32            // bsz * ENS
#define NPADC 32768
#define TARGETC 32640
#define LSEG 64           // items per segment
#define MSEG 512          // NPADC / LSEG
#define GSZ 32            // segments per group
#define NG 16             // MSEG / GSZ
#define SS 2

#define OFFS(i) ((i)*255 - (i)*((i)-1)/2)

// ---- cross-lane helpers on the VALU pipe (no ds_bpermute) ----
__device__ __forceinline__ int dpp_shr1_i(int v) {
    // wave_shr:1 (0x138), bound_ctrl=1 -> lane 0 receives 0
    return __builtin_amdgcn_mov_dpp(v, 0x138, 0xf, 0xf, true);
}
__device__ __forceinline__ double dpp_shr1_d(double v) {
    union { double d; int i[2]; } u; u.d = v;
    u.i[0] = dpp_shr1_i(u.i[0]);
    u.i[1] = dpp_shr1_i(u.i[1]);
    return u.d;
}
__device__ __forceinline__ double readlane_d(double v, int l) {
    union { double d; int i[2]; } u; u.d = v;
    union { double d; int i[2]; } r;
    r.i[0] = __builtin_amdgcn_readlane(u.i[0], l);
    r.i[1] = __builtin_amdgcn_readlane(u.i[1], l);
    return r.d;
}
__device__ __forceinline__ double readlane_f_to_d(float v, int l) {
    union { float f; int i; } u; u.f = v;
    union { float f; int i; } r;
    r.i = __builtin_amdgcn_readlane(u.i, l);
    return (double)r.f;
}

__device__ __forceinline__ void decode_ij(int t, int& oi, int& oj) {
    int ii = (int)((511.0 - sqrt(511.0 * 511.0 - 8.0 * (double)t)) * 0.5);
    if (ii < 0) ii = 0;
    if (ii > 254) ii = 254;
    while (ii < 254 && OFFS(ii + 1) <= t) ++ii;
    while (ii > 0 && OFFS(ii) > t) --ii;
    oi = ii;
    oj = t - OFFS(ii) + ii + 1;
}

// 33-point truncated polynomial product: out[r] = sum_j a[j]*b[r-j].
// a read via readlane (dependent operand), b rotated via DPP (independent).
__device__ __forceinline__ double conv33_rb(double a_dep, double b_rot) {
    double s0 = 0.0, s1 = 0.0, s2 = 0.0, s3 = 0.0;
    double brot = b_rot;
#pragma unroll
    for (int j = 0; j < KP; ++j) {
        double aj = readlane_d(a_dep, j);
        switch (j & 3) {
            case 0: s0 = fma(aj, brot, s0); break;
            case 1: s1 = fma(aj, brot, s1); break;
            case 2: s2 = fma(aj, brot, s2); break;
            default: s3 = fma(aj, brot, s3); break;
        }
        brot = dpp_shr1_d(brot);
    }
    return (s0 + s1) + (s2 + s3);
}

// ---- kernel 1: fused exp(theta) + per-segment elementary symmetric polys
__global__ void k_prep(const float* __restrict__ sc, double* __restrict__ X,
                       double* __restrict__ Bp) {
    int lane = threadIdx.x & 63;
    int blk = blockIdx.x * 4 + (threadIdx.x >> 6);   // b*MSEG + m
    int b = blk >> 9, m = blk & (MSEG - 1);
    int t = m * LSEG + lane;
    double x = 0.0;
    if (t < TARGETC) {
        int i, j;
        decode_ij(t, i, j);
        double th = (double)sc[((size_t)b * NMAXC + i) * NMAXC + j] +
                    (double)sc[((size_t)b * NMAXC + j) * NMAXC + i];
        x = exp(th);
    }
    X[(size_t)b * NPADC + t] = x;
    double c = (lane == 0) ? 1.0 : 0.0;
#pragma unroll
    for (int j = 0; j < LSEG; ++j) {
        double xj = readlane_d(x, j);
        double up = dpp_shr1_d(c);                   // lane0 -> 0
        c = fma(xj, up, c);
    }
    if (lane < KP) Bp[(size_t)blk * KP + lane] = c;
}

// ---- kernel 2: suffix-inclusive scan within group (1 wave/block, 512 blocks)
__global__ void k_gpart(const double* __restrict__ Bp,
                        double* __restrict__ sfxI, double* __restrict__ gpoly) {
    int lane = threadIdx.x;
    int blk = blockIdx.x;                 // b*NG + g
    int b = blk / NG, g = blk % NG;
    double run = (lane == 0) ? 1.0 : 0.0;
    int m = g * GSZ + (GSZ - 1);
    double bp = (lane < KP) ? Bp[((size_t)b * MSEG + m) * KP + lane] : 0.0;
    for (int i = GSZ - 1; i >= 0; --i) {
        int mi = g * GSZ + i;
        double bpn = (i > 0 && lane < KP) ? Bp[((size_t)b * MSEG + mi - 1) * KP + lane] : 0.0;
        run = conv33_rb(run, bp);         // dependent operand via readlane
        if (lane < KP) sfxI[((size_t)b * MSEG + mi) * KP + lane] = run;
        bp = bpn;
    }
    if (lane < KP) gpoly[(size_t)blk * KP + lane] = run;
}

// ---- kernel 3: suffix scan over group polys (exclusive carries) + full Z poly
__global__ void k_gscan(const double* __restrict__ gpoly, double* __restrict__ gcarry,
                        double* __restrict__ eZ) {
    int lane = threadIdx.x;
    int b = blockIdx.x;
    double run = (lane == 0) ? 1.0 : 0.0;
    double gp = (lane < KP) ? gpoly[((size_t)b * NG + NG - 1) * KP + lane] : 0.0;
    for (int g = NG - 1; g >= 0; --g) {
        if (lane < KP) gcarry[((size_t)b * NG + g) * KP + lane] = run;
        double gpn = (g > 0 && lane < KP) ? gpoly[((size_t)b * NG + g - 1) * KP + lane] : 0.0;
        run = conv33_rb(run, gp);
        gp = gpn;
    }
    if (lane < KP) eZ[(size_t)b * KP + lane] = run;   // e_0..e_K of all items
}

// ---- kernel 4: backward sfx sweep fused with sampling; entry checkpoint
//      reconstructed in-kernel (chkpt fused). 4 segments / block.
__global__ void k_backward(const double* __restrict__ X, const double* __restrict__ sfxI,
                           const double* __restrict__ gcarry, const float* __restrict__ U,
                           unsigned long long* __restrict__ masks, int* __restrict__ tab) {
    int lane = threadIdx.x & 63;
    int blk = blockIdx.x * 4 + (threadIdx.x >> 6);   // b*MSEG + m
    int b = blk >> 9, m = blk & (MSEG - 1);
    double xa = X[(size_t)b * NPADC + (size_t)m * LSEG + lane];
    float uf0 = U[((size_t)0 * NPADC + (size_t)m * LSEG + lane) * BCH + b];
    float uf1 = U[((size_t)1 * NPADC + (size_t)m * LSEG + lane) * BCH + b];
    double c;
    if (m + 1 == MSEG) {
        c = (lane == 0) ? 1.0 : 0.0;
    } else {
        double a  = (lane < KP) ? sfxI[((size_t)b * MSEG + m + 1) * KP + lane] : 0.0;
        double cg = (lane < KP) ? gcarry[((size_t)b * NG + (m + 1) / GSZ) * KP + lane] : 0.0;
        c = conv33_rb(cg, a);             // same op order as round-7 k_chkpt
        c = (lane < KP) ? c : 0.0;        // keep lanes>=33 identical to prior rounds
    }
    int S0 = lane, S1 = lane;
    unsigned long long mk0 = 0, mk1 = 0;
#pragma unroll
    for (int j = LSEG - 1; j >= 0; --j) {
        double xj = readlane_d(xa, j);
        double up = dpp_shr1_d(c);                   // sfx[j+1][lane-1], lane0 -> 0
        double rhs = xj * up;
        double cn = fma(xj, up, c);                  // sfx[j][lane]
        double ud0 = readlane_f_to_d(uf0, j);
        double ud1 = readlane_f_to_d(uf1, j);
        bool i0 = (ud0 * cn < rhs);                  // lane0: rhs==0 -> false
        bool i1 = (ud1 * cn < rhs);
        unsigned long long b0 = __ballot(i0);
        unsigned long long b1 = __ballot(i1);
        if (lane == j) { mk0 = b0; mk1 = b1; }       // SGPR->VGPR cndmask, no LDS
        int t0 = dpp_shr1_i(S0);
        int t1 = dpp_shr1_i(S1);
        if (i0) S0 = t0;
        if (i1) S1 = t1;
        c = cn;
    }
    size_t sb0 = (size_t)blk;
    size_t sb1 = (size_t)BCH * MSEG + blk;
    masks[sb0 * LSEG + lane] = mk0;
    masks[sb1 * LSEG + lane] = mk1;
    if (lane < KP) {
        tab[sb0 * KP + lane] = S0;
        tab[sb1 * KP + lane] = S1;
    }
}

// ---- kernel 5: hierarchical compose; per-wave tables kept in VGPRs
__global__ void __launch_bounds__(1024) k_compose(const int* __restrict__ tab,
                                                  int* __restrict__ rent) {
    __shared__ int gtab[NG][KP];
    __shared__ int gent[NG];
    int sb = blockIdx.x;                  // s*BCH + b
    int tid = threadIdx.x;                // 1024
    int w = tid >> 6, lane = tid & 63;
    int tv[GSZ];
    const int* base = tab + ((size_t)sb * MSEG + w * GSZ) * KP;
#pragma unroll
    for (int i = 0; i < GSZ; ++i)
        tv[i] = (lane < KP) ? base[i * KP + lane] : 0;
    int T = lane;                         // compose this wave's 32 segment maps
#pragma unroll
    for (int i = 0; i < GSZ; ++i)
        T = __shfl(tv[i], T, 64);
    if (lane < KP) gtab[w][lane] = T;
    __syncthreads();
    if (tid == 0) {
        int r = KK;
        for (int g = 0; g < NG; ++g) { gent[g] = r; r = gtab[g][r]; }
    }
    __syncthreads();
    int r = __builtin_amdgcn_readfirstlane(gent[w]);
    int rv = 0;
#pragma unroll
    for (int i = 0; i < GSZ; ++i) {       // scalar walk via readlane (no LDS chain)
        if (lane == i) rv = r;
        r = __builtin_amdgcn_readlane(tv[i], r);
    }
    if (lane < GSZ) rent[(size_t)sb * MSEG + w * GSZ + lane] = rv;
}

// ---- kernel 6: replay masks along realized path -> packed bitset (scalar path)
__global__ void k_replay(const unsigned long long* __restrict__ masks,
                         const int* __restrict__ rent, unsigned long long* __restrict__ bitflat) {
    int lane = threadIdx.x & 63;
    int blk = blockIdx.x * 4 + (threadIdx.x >> 6);   // sb*MSEG + m
    unsigned long long mv = masks[(size_t)blk * LSEG + lane];
    int mlo = (int)(unsigned)mv;
    int mhi = (int)(unsigned)(mv >> 32);
    int r = __builtin_amdgcn_readfirstlane(rent[blk]);
    unsigned long long sel = 0;
#pragma unroll
    for (int j = 0; j < LSEG; ++j) {
        unsigned lo = (unsigned)__builtin_amdgcn_readlane(mlo, j);
        unsigned hi = (unsigned)__builtin_amdgcn_readlane(mhi, j);
        unsigned long long mj = ((unsigned long long)hi << 32) | lo;
        int inc = (int)((mj >> r) & 1ull);
        sel |= ((unsigned long long)inc) << j;
        r -= inc;
    }
    if (lane == 0) bitflat[blk] = sel;
}

// ---- kernel 7: combined output emission.
//      gridDim.y in [0, SS*BCH): mask rows for chain sb = y
//      gridDim.y in [SS*BCH, SS*BCH+BCH): marginal rows for batch b = y - SS*BCH
__global__ void k_emit(const unsigned long long* __restrict__ bitflat,
                       const double* __restrict__ X, const double* __restrict__ eZ,
                       float* __restrict__ outMask, float* __restrict__ outMarg) {
    __shared__ unsigned long long bf[MSEG];
    __shared__ double e[KP];
    __shared__ double invZ;
    int y = blockIdx.y;
    int i = blockIdx.x;
    int j = threadIdx.x;                  // 256
    if (y < SS * BCH) {
        int sb = y;
        bf[j] = bitflat[(size_t)sb * MSEG + j];
        bf[j + 256] = bitflat[(size_t)sb * MSEG + 256 + j];
        __syncthreads();
        float v = 0.0f;
        if (j > i) {
            int t = OFFS(i) + j - i - 1;
            v = (float)((bf[t >> 6] >> (t & 63)) & 1ull);
        } else if (j < i) {
            int t = OFFS(j) + i - j - 1;
            v = (float)((bf[t >> 6] >> (t & 63)) & 1ull);
        }
        outMask[((size_t)sb * NMAXC + i) * NMAXC + j] = v;
    } else {
        int b = y - SS * BCH;
        if (j < KP) e[j] = eZ[(size_t)b * KP + j];
        __syncthreads();
        if (j == 0) invZ = 1.0 / e[KK];
        __syncthreads();
        float v = 0.0f;
        if (i != j) {
            int t = (j > i) ? (OFFS(i) + j - i - 1) : (OFFS(j) + i - j - 1);
            double x = X[(size_t)b * NPADC + t];
            double f = 1.0;
#pragma unroll
            for (int k = 1; k < KK; ++k) f = fma(-x, f, e[k]);
            v = (float)(x * f * invZ);
        }
        outMarg[((size_t)b * NMAXC + i) * NMAXC + j] = v;
    }
}

extern "C" void kernel_launch(void* const* d_in, const int* in_sizes, int n_in,
                              void* d_out, int out_size, void* d_ws, size_t ws_size,
                              hipStream_t stream) {
    const float* scores = (const float*)d_in[0];
    const float* uniforms = (const float*)d_in[1];

    char* ws = (char*)d_ws;
    size_t off = 0;
    auto alloc = [&](size_t bytes) {
        void* p = ws + off;
        off += (bytes + 255) & ~(size_t)255;
        return p;
    };
    double* X      = (double*)alloc((size_t)BCH * NPADC * 8);
    double* Bp     = (double*)alloc((size_t)BCH * MSEG * KP * 8);
    double* sfxI   = (double*)alloc((size_t)BCH * MSEG * KP * 8);
    double* gpoly  = (double*)alloc((size_t)BCH * NG * KP * 8);
    double* gcarry = (double*)alloc((size_t)BCH * NG * KP * 8);
    double* eZ     = (double*)alloc((size_t)BCH * KP * 8);
    unsigned long long* masks = (unsigned long long*)alloc((size_t)SS * BCH * MSEG * LSEG * 8);
    int* tab       = (int*)alloc((size_t)SS * BCH * MSEG * KP * 4);
    int* rent      = (int*)alloc((size_t)SS * BCH * MSEG * 4);
    unsigned long long* bitflat = (unsigned long long*)alloc((size_t)SS * BCH * MSEG * 8);
    if (off > ws_size) return;            // ~38 MB

    k_prep<<<BCH * MSEG / 4, 256, 0, stream>>>(scores, X, Bp);
    k_gpart<<<BCH * NG, 64, 0, stream>>>(Bp, sfxI, gpoly);
    k_gscan<<<BCH, 64, 0, stream>>>(gpoly, gcarry, eZ);
    k_backward<<<BCH * MSEG / 4, 256, 0, stream>>>(X, sfxI, gcarry, uniforms, masks, tab);
    k_compose<<<SS * BCH, 1024, 0, stream>>>(tab, rent);
    k_replay<<<SS * BCH * MSEG / 4, 256, 0, stream>>>(masks, rent, bitflat);
    k_emit<<<dim3(NMAXC, SS * BCH + BCH), 256, 0, stream>>>(
        bitflat, X, eZ, (float*)d_out,
        (float*)d_out + (size_t)SS * BCH * NMAXC * NMAXC);
}